// Round 1
// baseline (390.233 us; speedup 1.0000x reference)
//
#include <hip/hip_runtime.h>

#define NE 100000   // edges
#define NN 50000    // nodes

// ---------------------------------------------------------------------------
// QKV kernel: q|k|v = x @ [Wq|Wk|Wv],  x = [ef | node[src] | node[dst]] (E x 192)
// Block: 256 threads, BM=64 edges, all 192 output cols. Micro-tile 4 rows x 12 cols.
// ---------------------------------------------------------------------------
__global__ __launch_bounds__(256) void qkv_kernel(
    const float* __restrict__ ef, const float* __restrict__ nodef,
    const int* __restrict__ eidx,
    const float* __restrict__ Wq, const float* __restrict__ Wk,
    const float* __restrict__ Wv,
    float* __restrict__ qo, float* __restrict__ ko, float* __restrict__ vo)
{
    __shared__ __align__(16) float xs[64][64];    // [k][m]  (k-major: conflict-free)
    __shared__ __align__(16) float wsh[64][192];  // [k][c]

    const int tid  = threadIdx.x;
    const int e0   = blockIdx.x * 64;
    const int tr   = tid >> 4;   // 0..15 row group
    const int tc   = tid & 15;   // 0..15 col group
    const int wave = tid >> 6;   // 0..3
    const int lane = tid & 63;

    float acc[4][12];
    #pragma unroll
    for (int i = 0; i < 4; ++i)
        #pragma unroll
        for (int j = 0; j < 12; ++j) acc[i][j] = 0.f;

    for (int ch = 0; ch < 3; ++ch) {
        // ---- stage x chunk, transposed into xs[k][m] ----
        {
            const int m = lane;
            const int e = e0 + m;
            const float* src = nullptr;
            if (e < NE) {
                if (ch == 0)      src = ef    + (size_t)e * 64;
                else if (ch == 1) src = nodef + (size_t)eidx[e] * 64;
                else              src = nodef + (size_t)eidx[NE + e] * 64;
            }
            const int kb = wave * 16;
            #pragma unroll
            for (int j = 0; j < 4; ++j) {
                float4 val = make_float4(0.f, 0.f, 0.f, 0.f);
                if (src) val = *(const float4*)(src + kb + j * 4);
                xs[kb + j*4 + 0][m] = val.x;
                xs[kb + j*4 + 1][m] = val.y;
                xs[kb + j*4 + 2][m] = val.z;
                xs[kb + j*4 + 3][m] = val.w;
            }
        }
        // ---- stage W chunk: wsh[k][0:64]=Wq row, [64:128]=Wk, [128:192]=Wv ----
        {
            #pragma unroll
            for (int r = 0; r < 12; ++r) {
                int f  = tid + 256 * r;        // 0..3071 float4 slots (64 x 48)
                int kk = f / 48;
                int c4 = f % 48;
                int kg = ch * 64 + kk;
                const float* wp = (c4 < 16) ? Wq : (c4 < 32) ? Wk : Wv;
                int cc = (c4 & 15) * 4;
                *(float4*)(&wsh[kk][c4 * 4]) =
                    *(const float4*)(wp + (size_t)kg * 64 + cc);
            }
        }
        __syncthreads();
        // ---- compute ----
        #pragma unroll 8
        for (int kk = 0; kk < 64; ++kk) {
            float4 xv = *(const float4*)(&xs[kk][tr * 4]);
            float4 w0 = *(const float4*)(&wsh[kk][tc * 12 + 0]);
            float4 w1 = *(const float4*)(&wsh[kk][tc * 12 + 4]);
            float4 w2 = *(const float4*)(&wsh[kk][tc * 12 + 8]);
            float xr[4]  = {xv.x, xv.y, xv.z, xv.w};
            float wr[12] = {w0.x, w0.y, w0.z, w0.w,
                            w1.x, w1.y, w1.z, w1.w,
                            w2.x, w2.y, w2.z, w2.w};
            #pragma unroll
            for (int i = 0; i < 4; ++i)
                #pragma unroll
                for (int j = 0; j < 12; ++j)
                    acc[i][j] = fmaf(xr[i], wr[j], acc[i][j]);
        }
        __syncthreads();
    }

    // ---- store: col c<64 -> q, <128 -> k, else v (float4 never straddles) ----
    #pragma unroll
    for (int i = 0; i < 4; ++i) {
        int e = e0 + tr * 4 + i;
        if (e >= NE) continue;
        #pragma unroll
        for (int j = 0; j < 3; ++j) {
            int c = tc * 12 + j * 4;
            float4 val = make_float4(acc[i][j*4+0], acc[i][j*4+1],
                                     acc[i][j*4+2], acc[i][j*4+3]);
            float* dst;
            if (c < 64)       dst = qo + (size_t)e * 64 + c;
            else if (c < 128) dst = ko + (size_t)e * 64 + (c - 64);
            else              dst = vo + (size_t)e * 64 + (c - 128);
            *(float4*)dst = val;
        }
    }
}

// ---------------------------------------------------------------------------
// Attention: one wave per dst edge. adj_dst == repeat(arange(E), 8) by
// construction, so edge e's neighbors live at adj slots e*8 .. e*8+7.
// lane = h*16 + d (h = lane>>4). Writes result into `out` (aliases q buffer:
// q[e] is only ever read by the wave that owns e, so in-place is safe).
// ---------------------------------------------------------------------------
__global__ __launch_bounds__(256) void attn_kernel(
    const float* __restrict__ q, const float* __restrict__ kbuf,
    const float* __restrict__ vbuf, const int* __restrict__ adj_src,
    float* __restrict__ out)
{
    const int wid  = (blockIdx.x * 256 + threadIdx.x) >> 6;
    const int lane = threadIdx.x & 63;
    if (wid >= NE) return;
    const int e = wid;

    const float qval = q[(size_t)e * 64 + lane];
    int   nbr[8];
    float s[8];
    #pragma unroll
    for (int j = 0; j < 8; ++j) {
        nbr[j] = adj_src[e * 8 + j];
        float p = qval * kbuf[(size_t)nbr[j] * 64 + lane];
        p += __shfl_xor(p, 1);
        p += __shfl_xor(p, 2);
        p += __shfl_xor(p, 4);
        p += __shfl_xor(p, 8);   // sum over the 16 lanes of this head
        s[j] = p * 0.25f;        // 1/sqrt(16)
    }
    float m = s[0];
    #pragma unroll
    for (int j = 1; j < 8; ++j) m = fmaxf(m, s[j]);
    float den = 0.f, w[8];
    #pragma unroll
    for (int j = 0; j < 8; ++j) { w[j] = __expf(s[j] - m); den += w[j]; }
    const float inv = 1.f / den;

    float o = 0.f;
    #pragma unroll
    for (int j = 0; j < 8; ++j)
        o = fmaf(w[j] * inv, vbuf[(size_t)nbr[j] * 64 + lane], o);
    out[(size_t)e * 64 + lane] = o;
}

// ---------------------------------------------------------------------------
// Output projection + residual: ef_out = ef_in + attn_out @ Wo
// Same GEMM skeleton, K=N=64, 4x4 micro-tile. ef_in may alias ef_out
// (element read and written by the same thread only).
// ---------------------------------------------------------------------------
__global__ __launch_bounds__(256) void wo_kernel(
    const float* __restrict__ ef_in, const float* __restrict__ attn_out,
    const float* __restrict__ Wo, float* __restrict__ ef_out)
{
    __shared__ __align__(16) float xs[64][64];   // [k][m]
    __shared__ __align__(16) float wsh[64][64];  // [k][c]

    const int tid  = threadIdx.x;
    const int e0   = blockIdx.x * 64;
    const int tr   = tid >> 4;
    const int tc   = tid & 15;
    const int wave = tid >> 6;
    const int lane = tid & 63;

    // stage attn_out rows transposed
    {
        const int m = lane;
        const int e = e0 + m;
        const int kb = wave * 16;
        #pragma unroll
        for (int j = 0; j < 4; ++j) {
            float4 val = make_float4(0.f, 0.f, 0.f, 0.f);
            if (e < NE) val = *(const float4*)(attn_out + (size_t)e * 64 + kb + j * 4);
            xs[kb + j*4 + 0][m] = val.x;
            xs[kb + j*4 + 1][m] = val.y;
            xs[kb + j*4 + 2][m] = val.z;
            xs[kb + j*4 + 3][m] = val.w;
        }
    }
    // stage Wo
    for (int f = tid; f < 64 * 16; f += 256) {
        int kk = f >> 4, c4 = (f & 15) * 4;
        *(float4*)(&wsh[kk][c4]) = *(const float4*)(Wo + (size_t)kk * 64 + c4);
    }
    __syncthreads();

    float acc[4][4] = {};
    #pragma unroll 8
    for (int kk = 0; kk < 64; ++kk) {
        float4 xv = *(const float4*)(&xs[kk][tr * 4]);
        float4 wv = *(const float4*)(&wsh[kk][tc * 4]);
        float xr[4] = {xv.x, xv.y, xv.z, xv.w};
        float wr[4] = {wv.x, wv.y, wv.z, wv.w};
        #pragma unroll
        for (int i = 0; i < 4; ++i)
            #pragma unroll
            for (int j = 0; j < 4; ++j)
                acc[i][j] = fmaf(xr[i], wr[j], acc[i][j]);
    }

    #pragma unroll
    for (int i = 0; i < 4; ++i) {
        int e = e0 + tr * 4 + i;
        if (e >= NE) continue;
        float4 r = *(const float4*)(ef_in + (size_t)e * 64 + tc * 4);
        float4 val = make_float4(acc[i][0] + r.x, acc[i][1] + r.y,
                                 acc[i][2] + r.z, acc[i][3] + r.w);
        *(float4*)(ef_out + (size_t)e * 64 + tc * 4) = val;
    }
}

// ---------------------------------------------------------------------------
extern "C" void kernel_launch(void* const* d_in, const int* in_sizes, int n_in,
                              void* d_out, int out_size, void* d_ws, size_t ws_size,
                              hipStream_t stream)
{
    const float* nodef   = (const float*)d_in[0];
    const float* ef      = (const float*)d_in[1];
    const int*   eidx    = (const int*)d_in[2];   // [2,E]: [0..E)=src, [E..2E)=dst
    // d_in[3] node_tiers: unused by reference output
    const int*   adj_src = (const int*)d_in[4];
    // d_in[5] adj_dst: == repeat(arange(E),8) by construction
    const float* l1Wq = (const float*)d_in[6];
    const float* l1Wk = (const float*)d_in[7];
    const float* l1Wv = (const float*)d_in[8];
    const float* l1Wo = (const float*)d_in[9];
    const float* l2Wq = (const float*)d_in[10];
    const float* l2Wk = (const float*)d_in[11];
    const float* l2Wv = (const float*)d_in[12];
    const float* l2Wo = (const float*)d_in[13];

    float* q = (float*)d_ws;                 // [E,64]
    float* k = q + (size_t)NE * 64;          // [E,64]
    float* v = k + (size_t)NE * 64;          // [E,64]
    float* out = (float*)d_out;              // [E,64]

    dim3 blk(256);
    const int gq = (NE + 63) / 64;   // 1563
    const int ga = (NE + 3) / 4;     // 25000

    // ---- layer 1 ----
    qkv_kernel<<<gq, blk, 0, stream>>>(ef, nodef, eidx, l1Wq, l1Wk, l1Wv, q, k, v);
    attn_kernel<<<ga, blk, 0, stream>>>(q, k, v, adj_src, q);
    wo_kernel<<<gq, blk, 0, stream>>>(ef, q, l1Wo, out);
    // ---- layer 2 (edge features = layer-1 output in d_out) ----
    qkv_kernel<<<gq, blk, 0, stream>>>(out, nodef, eidx, l2Wq, l2Wk, l2Wv, q, k, v);
    attn_kernel<<<ga, blk, 0, stream>>>(q, k, v, adj_src, q);
    wo_kernel<<<gq, blk, 0, stream>>>(out, q, l2Wo, out);
}

// Round 2
// 250.487 us; speedup vs baseline: 1.5579x; 1.5579x over previous
//
#include <hip/hip_runtime.h>

#define NE 100000   // edges
#define NN 50000    // nodes

typedef short short8 __attribute__((ext_vector_type(8)));
typedef float f32x4 __attribute__((ext_vector_type(4)));

// fp32 -> bf16 bits, round-to-nearest-even
__device__ inline unsigned short f2bf(float f) {
    unsigned int u = __float_as_uint(f);
    u += 0x7FFFu + ((u >> 16) & 1u);
    return (unsigned short)(u >> 16);
}

__device__ inline short8 pack_bf8(float4 a, float4 b) {
    short8 r;
    r[0] = (short)f2bf(a.x); r[1] = (short)f2bf(a.y);
    r[2] = (short)f2bf(a.z); r[3] = (short)f2bf(a.w);
    r[4] = (short)f2bf(b.x); r[5] = (short)f2bf(b.y);
    r[6] = (short)f2bf(b.z); r[7] = (short)f2bf(b.w);
    return r;
}

// ---------------------------------------------------------------------------
// Prep: pack W = [Wq|Wk|Wv] (each [192,64] fp32) into bf16 B-fragment order:
// wf[((s*12 + t)*64 + lane)*8 + j] = W[k = 32s + (lane>>4)*8 + j][n = 16t + (lane&15)]
// 6 ksteps x 12 ntiles x 64 lanes = 4608 fragment slots.
// ---------------------------------------------------------------------------
__global__ __launch_bounds__(256) void prep_qkv_w(
    const float* __restrict__ Wq, const float* __restrict__ Wk,
    const float* __restrict__ Wv, unsigned short* __restrict__ wf)
{
    int idx = blockIdx.x * 256 + threadIdx.x;
    if (idx >= 6 * 12 * 64) return;
    int lane = idx & 63;
    int st = idx >> 6;
    int s = st / 12, t = st % 12;
    int n = t * 16 + (lane & 15);
    int kb = s * 32 + (lane >> 4) * 8;
    const float* w = (n < 64) ? Wq : (n < 128) ? Wk : Wv;
    int nn = n & 63;
    unsigned short o[8];
    #pragma unroll
    for (int j = 0; j < 8; ++j) o[j] = f2bf(w[(size_t)(kb + j) * 64 + nn]);
    #pragma unroll
    for (int j = 0; j < 8; ++j) wf[(size_t)idx * 8 + j] = o[j];
}

// Same packing for Wo [64,64]: 2 ksteps x 4 ntiles x 64 lanes = 512 slots.
__global__ __launch_bounds__(256) void prep_wo_w(
    const float* __restrict__ Wo, unsigned short* __restrict__ wf)
{
    int idx = blockIdx.x * 256 + threadIdx.x;
    if (idx >= 2 * 4 * 64) return;
    int lane = idx & 63;
    int st = idx >> 6;
    int s = st / 4, t = st % 4;
    int n = t * 16 + (lane & 15);
    int kb = s * 32 + (lane >> 4) * 8;
    unsigned short o[8];
    #pragma unroll
    for (int j = 0; j < 8; ++j) o[j] = f2bf(Wo[(size_t)(kb + j) * 64 + n]);
    #pragma unroll
    for (int j = 0; j < 8; ++j) wf[(size_t)idx * 8 + j] = o[j];
}

// ---------------------------------------------------------------------------
// QKV GEMM via MFMA: one wave per 16 edge-rows, all 192 output cols.
// x-row = [ef[e] | node[src] | node[dst]], gathered from global, cvt to bf16.
// No LDS, no barriers; W read from pre-packed fragment buffer (L1/L2-hot).
// ---------------------------------------------------------------------------
__global__ __launch_bounds__(256) void qkv_mfma(
    const float* __restrict__ ef, const float* __restrict__ nodef,
    const int* __restrict__ eidx, const unsigned short* __restrict__ wfrag,
    float* __restrict__ qo, float* __restrict__ ko, float* __restrict__ vo)
{
    const int wave = threadIdx.x >> 6;
    const int lane = threadIdx.x & 63;
    const int r  = lane & 15;    // A row within 16-tile / D col within 16-tile
    const int kg = lane >> 4;    // k-group 0..3
    const int e0 = blockIdx.x * 64 + wave * 16;
    const int e  = e0 + r;
    const int ec = (e < NE) ? e : NE - 1;

    const float* rp0 = ef    + (size_t)ec * 64;
    const float* rp1 = nodef + (size_t)eidx[ec] * 64;
    const float* rp2 = nodef + (size_t)eidx[NE + ec] * 64;

    // A fragments for all 6 K-steps (K = 192)
    short8 afr[6];
    #pragma unroll
    for (int s = 0; s < 6; ++s) {
        const float* bp = ((s < 2) ? rp0 : (s < 4) ? rp1 : rp2) + (s & 1) * 32 + kg * 8;
        afr[s] = pack_bf8(*(const float4*)bp, *(const float4*)(bp + 4));
    }

    const short8* wf = (const short8*)wfrag;
    f32x4 acc[12];
    #pragma unroll
    for (int t = 0; t < 12; ++t) acc[t] = (f32x4)(0.f);

    #pragma unroll
    for (int s = 0; s < 6; ++s) {
        #pragma unroll
        for (int t = 0; t < 12; ++t) {
            short8 b = wf[(size_t)(s * 12 + t) * 64 + lane];
            acc[t] = __builtin_amdgcn_mfma_f32_16x16x32_bf16(afr[s], b, acc[t], 0, 0, 0);
        }
    }

    // D layout: col = lane&15 (=r), row = kg*4 + j
    const int orow = e0 + kg * 4;
    #pragma unroll
    for (int t = 0; t < 12; ++t) {
        const int c = t * 16 + r;
        float* dst = (c < 64) ? (qo + c) : (c < 128) ? (ko + (c - 64)) : (vo + (c - 128));
        #pragma unroll
        for (int j = 0; j < 4; ++j) {
            int row = orow + j;
            if (row < NE) dst[(size_t)row * 64] = acc[t][j];
        }
    }
}

// ---------------------------------------------------------------------------
// Attention: one wave per dst edge (neighbors at adj slots e*8..e*8+7).
// lane = h*16 + d. Writes in-place into q (only this wave reads q[e]).
// ---------------------------------------------------------------------------
__global__ __launch_bounds__(256) void attn_kernel(
    const float* __restrict__ q, const float* __restrict__ kbuf,
    const float* __restrict__ vbuf, const int* __restrict__ adj_src,
    float* __restrict__ out)
{
    const int wid  = (blockIdx.x * 256 + threadIdx.x) >> 6;
    const int lane = threadIdx.x & 63;
    if (wid >= NE) return;
    const int e = wid;

    const float qval = q[(size_t)e * 64 + lane];
    int   nbr[8];
    float s[8];
    #pragma unroll
    for (int j = 0; j < 8; ++j) {
        nbr[j] = adj_src[e * 8 + j];
        float p = qval * kbuf[(size_t)nbr[j] * 64 + lane];
        p += __shfl_xor(p, 1);
        p += __shfl_xor(p, 2);
        p += __shfl_xor(p, 4);
        p += __shfl_xor(p, 8);   // sum over 16 lanes of this head
        s[j] = p * 0.25f;        // 1/sqrt(16)
    }
    float m = s[0];
    #pragma unroll
    for (int j = 1; j < 8; ++j) m = fmaxf(m, s[j]);
    float den = 0.f, w[8];
    #pragma unroll
    for (int j = 0; j < 8; ++j) { w[j] = __expf(s[j] - m); den += w[j]; }
    const float inv = 1.f / den;

    float o = 0.f;
    #pragma unroll
    for (int j = 0; j < 8; ++j)
        o = fmaf(w[j] * inv, vbuf[(size_t)nbr[j] * 64 + lane], o);
    out[(size_t)e * 64 + lane] = o;
}

// ---------------------------------------------------------------------------
// Wo GEMM via MFMA + fused residual: out = ef_in + attn @ Wo.
// One wave per 16 rows x 64 cols. ef_in may alias out (same-thread rmw).
// ---------------------------------------------------------------------------
__global__ __launch_bounds__(256) void wo_mfma(
    const float* __restrict__ ef_in, const float* __restrict__ attn,
    const unsigned short* __restrict__ wofrag, float* __restrict__ efo)
{
    const int wave = threadIdx.x >> 6;
    const int lane = threadIdx.x & 63;
    const int r  = lane & 15;
    const int kg = lane >> 4;
    const int e0 = blockIdx.x * 64 + wave * 16;
    const int e  = e0 + r;
    const int ec = (e < NE) ? e : NE - 1;

    short8 afr[2];
    #pragma unroll
    for (int s = 0; s < 2; ++s) {
        const float* bp = attn + (size_t)ec * 64 + s * 32 + kg * 8;
        afr[s] = pack_bf8(*(const float4*)bp, *(const float4*)(bp + 4));
    }

    const short8* wf = (const short8*)wofrag;
    f32x4 acc[4];
    #pragma unroll
    for (int t = 0; t < 4; ++t) acc[t] = (f32x4)(0.f);
    #pragma unroll
    for (int s = 0; s < 2; ++s) {
        #pragma unroll
        for (int t = 0; t < 4; ++t) {
            short8 b = wf[(size_t)(s * 4 + t) * 64 + lane];
            acc[t] = __builtin_amdgcn_mfma_f32_16x16x32_bf16(afr[s], b, acc[t], 0, 0, 0);
        }
    }

    const int orow = e0 + kg * 4;
    #pragma unroll
    for (int t = 0; t < 4; ++t) {
        const int c = t * 16 + r;
        #pragma unroll
        for (int j = 0; j < 4; ++j) {
            int row = orow + j;
            if (row < NE) {
                size_t off = (size_t)row * 64 + c;
                efo[off] = acc[t][j] + ef_in[off];
            }
        }
    }
}

// ---------------------------------------------------------------------------
extern "C" void kernel_launch(void* const* d_in, const int* in_sizes, int n_in,
                              void* d_out, int out_size, void* d_ws, size_t ws_size,
                              hipStream_t stream)
{
    const float* nodef   = (const float*)d_in[0];
    const float* ef      = (const float*)d_in[1];
    const int*   eidx    = (const int*)d_in[2];   // [2,E]
    const int*   adj_src = (const int*)d_in[4];
    const float* l1Wq = (const float*)d_in[6];
    const float* l1Wk = (const float*)d_in[7];
    const float* l1Wv = (const float*)d_in[8];
    const float* l1Wo = (const float*)d_in[9];
    const float* l2Wq = (const float*)d_in[10];
    const float* l2Wk = (const float*)d_in[11];
    const float* l2Wv = (const float*)d_in[12];
    const float* l2Wo = (const float*)d_in[13];

    float* q = (float*)d_ws;                 // [E,64]
    float* k = q + (size_t)NE * 64;
    float* v = k + (size_t)NE * 64;
    unsigned short* wf1 = (unsigned short*)(v + (size_t)NE * 64); // 36864 each
    unsigned short* wf2 = wf1 + 36864;
    unsigned short* wo1 = wf2 + 36864;       // 4096 each
    unsigned short* wo2 = wo1 + 4096;
    float* out = (float*)d_out;

    dim3 blk(256);
    const int gq = (NE + 63) / 64;   // 1563 (64 rows / block, 4 waves)
    const int ga = (NE + 3) / 4;     // 25000

    // pack weights (bf16, fragment-ordered)
    prep_qkv_w<<<18, blk, 0, stream>>>(l1Wq, l1Wk, l1Wv, wf1);
    prep_qkv_w<<<18, blk, 0, stream>>>(l2Wq, l2Wk, l2Wv, wf2);
    prep_wo_w<<<2, blk, 0, stream>>>(l1Wo, wo1);
    prep_wo_w<<<2, blk, 0, stream>>>(l2Wo, wo2);

    // ---- layer 1 ----
    qkv_mfma<<<gq, blk, 0, stream>>>(ef, nodef, eidx, wf1, q, k, v);
    attn_kernel<<<ga, blk, 0, stream>>>(q, k, v, adj_src, q);
    wo_mfma<<<gq, blk, 0, stream>>>(ef, q, wo1, out);
    // ---- layer 2 ----
    qkv_mfma<<<gq, blk, 0, stream>>>(out, nodef, eidx, wf2, q, k, v);
    attn_kernel<<<ga, blk, 0, stream>>>(q, k, v, adj_src, q);
    wo_mfma<<<gq, blk, 0, stream>>>(out, q, wo2, out);
}

// Round 3
// 170.000 us; speedup vs baseline: 2.2955x; 1.4735x over previous
//
#include <hip/hip_runtime.h>

#define NE 100000   // edges
#define NN 50000    // nodes

typedef short short8 __attribute__((ext_vector_type(8)));
typedef float f32x4 __attribute__((ext_vector_type(4)));
typedef unsigned short ushort;

// fp32 -> bf16 bits, round-to-nearest-even
__device__ inline ushort f2bf(float f) {
    unsigned int u = __float_as_uint(f);
    u += 0x7FFFu + ((u >> 16) & 1u);
    return (ushort)(u >> 16);
}
__device__ inline float bf2f(ushort u) {
    return __uint_as_float((unsigned int)u << 16);
}

__device__ inline short8 pack_bf8(float4 a, float4 b) {
    short8 r;
    r[0] = (short)f2bf(a.x); r[1] = (short)f2bf(a.y);
    r[2] = (short)f2bf(a.z); r[3] = (short)f2bf(a.w);
    r[4] = (short)f2bf(b.x); r[5] = (short)f2bf(b.y);
    r[6] = (short)f2bf(b.z); r[7] = (short)f2bf(b.w);
    return r;
}

// ---------------------------------------------------------------------------
// Prep: pack W = [Wq|Wk|Wv] (each [192,64] fp32) into bf16 B-fragment order:
// wf[((s*12 + t)*64 + lane)*8 + j] = W[k = 32s + (lane>>4)*8 + j][n = 16t + (lane&15)]
// ---------------------------------------------------------------------------
__global__ __launch_bounds__(256) void prep_qkv_w(
    const float* __restrict__ Wq, const float* __restrict__ Wk,
    const float* __restrict__ Wv, ushort* __restrict__ wf)
{
    int idx = blockIdx.x * 256 + threadIdx.x;
    if (idx >= 6 * 12 * 64) return;
    int lane = idx & 63;
    int st = idx >> 6;
    int s = st / 12, t = st % 12;
    int n = t * 16 + (lane & 15);
    int kb = s * 32 + (lane >> 4) * 8;
    const float* w = (n < 64) ? Wq : (n < 128) ? Wk : Wv;
    int nn = n & 63;
    #pragma unroll
    for (int j = 0; j < 8; ++j)
        wf[(size_t)idx * 8 + j] = f2bf(w[(size_t)(kb + j) * 64 + nn]);
}

// Same packing for Wo [64,64]: 2 ksteps x 4 ntiles x 64 lanes = 512 slots.
__global__ __launch_bounds__(256) void prep_wo_w(
    const float* __restrict__ Wo, ushort* __restrict__ wf)
{
    int idx = blockIdx.x * 256 + threadIdx.x;
    if (idx >= 2 * 4 * 64) return;
    int lane = idx & 63;
    int st = idx >> 6;
    int s = st / 4, t = st % 4;
    int n = t * 16 + (lane & 15);
    int kb = s * 32 + (lane >> 4) * 8;
    #pragma unroll
    for (int j = 0; j < 8; ++j)
        wf[(size_t)idx * 8 + j] = f2bf(Wo[(size_t)(kb + j) * 64 + n]);
}

// ---------------------------------------------------------------------------
// QKV GEMM via MFMA: one wave per 32 edge-rows (two 16-row A tiles sharing
// each B fragment), all 192 output cols. Outputs bf16 q/k/v.
// ---------------------------------------------------------------------------
__global__ __launch_bounds__(256) void qkv_mfma(
    const float* __restrict__ ef, const float* __restrict__ nodef,
    const int* __restrict__ eidx, const ushort* __restrict__ wfrag,
    ushort* __restrict__ qo, ushort* __restrict__ ko, ushort* __restrict__ vo)
{
    const int wave = threadIdx.x >> 6;
    const int lane = threadIdx.x & 63;
    const int r  = lane & 15;
    const int kg = lane >> 4;
    const int e0 = blockIdx.x * 128 + wave * 32;
    const int eA = e0 + r;
    const int eB = e0 + 16 + r;
    const int eAc = (eA < NE) ? eA : NE - 1;
    const int eBc = (eB < NE) ? eB : NE - 1;

    const float* pA[3] = { ef    + (size_t)eAc * 64,
                           nodef + (size_t)eidx[eAc] * 64,
                           nodef + (size_t)eidx[NE + eAc] * 64 };
    const float* pB[3] = { ef    + (size_t)eBc * 64,
                           nodef + (size_t)eidx[eBc] * 64,
                           nodef + (size_t)eidx[NE + eBc] * 64 };

    const short8* wf = (const short8*)wfrag;
    f32x4 acc0[12], acc1[12];
    #pragma unroll
    for (int t = 0; t < 12; ++t) { acc0[t] = (f32x4)(0.f); acc1[t] = (f32x4)(0.f); }

    #pragma unroll
    for (int s = 0; s < 6; ++s) {
        const float* ba = pA[s >> 1] + (s & 1) * 32 + kg * 8;
        const float* bb = pB[s >> 1] + (s & 1) * 32 + kg * 8;
        short8 a0 = pack_bf8(*(const float4*)ba, *(const float4*)(ba + 4));
        short8 a1 = pack_bf8(*(const float4*)bb, *(const float4*)(bb + 4));
        #pragma unroll
        for (int t = 0; t < 12; ++t) {
            short8 b = wf[(size_t)(s * 12 + t) * 64 + lane];
            acc0[t] = __builtin_amdgcn_mfma_f32_16x16x32_bf16(a0, b, acc0[t], 0, 0, 0);
            acc1[t] = __builtin_amdgcn_mfma_f32_16x16x32_bf16(a1, b, acc1[t], 0, 0, 0);
        }
    }

    // D layout: col = lane&15 (=r), row = kg*4 + j
    const int orow0 = e0 + kg * 4;
    const int orow1 = e0 + 16 + kg * 4;
    #pragma unroll
    for (int t = 0; t < 12; ++t) {
        const int c = t * 16 + r;
        ushort* dst = (c < 64) ? (qo + c) : (c < 128) ? (ko + (c - 64)) : (vo + (c - 128));
        #pragma unroll
        for (int j = 0; j < 4; ++j) {
            int row0 = orow0 + j;
            int row1 = orow1 + j;
            if (row0 < NE) dst[(size_t)row0 * 64] = f2bf(acc0[t][j]);
            if (row1 < NE) dst[(size_t)row1 * 64] = f2bf(acc1[t][j]);
        }
    }
}

// ---------------------------------------------------------------------------
// Attention: one wave per dst edge (neighbors at adj slots e*8..e*8+7).
// lane = half*32 + h*8 + dd: handles dim-pair (2dd,2dd+1) of head h for
// neighbors with parity `half`. All bf16 in/out, fp32 math.
// ---------------------------------------------------------------------------
__global__ __launch_bounds__(256) void attn_kernel(
    const ushort* __restrict__ q, const ushort* __restrict__ kbuf,
    const ushort* __restrict__ vbuf, const int* __restrict__ adj_src,
    ushort* __restrict__ ao)
{
    const int wid  = (blockIdx.x * 256 + threadIdx.x) >> 6;
    const int lane = threadIdx.x & 63;
    if (wid >= NE) return;
    const int e    = wid;
    const int half = lane >> 5;
    const int l32  = lane & 31;          // dim-pair index within the row

    ushort2 qu = *(const ushort2*)(q + (size_t)e * 64 + l32 * 2);
    const float q0 = bf2f(qu.x), q1 = bf2f(qu.y);

    int nbr[4];
    float s[4];
    #pragma unroll
    for (int t = 0; t < 4; ++t) {
        nbr[t] = adj_src[e * 8 + 2 * t + half];
        ushort2 ku = *(const ushort2*)(kbuf + (size_t)nbr[t] * 64 + l32 * 2);
        float p = q0 * bf2f(ku.x) + q1 * bf2f(ku.y);
        p += __shfl_xor(p, 1);
        p += __shfl_xor(p, 2);
        p += __shfl_xor(p, 4);           // sum over the 8 lanes of this head
        s[t] = p * 0.25f;                // 1/sqrt(16)
    }

    float m = fmaxf(fmaxf(s[0], s[1]), fmaxf(s[2], s[3]));
    m = fmaxf(m, __shfl_xor(m, 32));     // combine neighbor parities
    float w[4], den = 0.f;
    #pragma unroll
    for (int t = 0; t < 4; ++t) { w[t] = __expf(s[t] - m); den += w[t]; }
    den += __shfl_xor(den, 32);
    const float inv = 1.f / den;

    float ox = 0.f, oy = 0.f;
    #pragma unroll
    for (int t = 0; t < 4; ++t) {
        ushort2 vu = *(const ushort2*)(vbuf + (size_t)nbr[t] * 64 + l32 * 2);
        ox = fmaf(w[t], bf2f(vu.x), ox);
        oy = fmaf(w[t], bf2f(vu.y), oy);
    }
    ox = (ox + __shfl_xor(ox, 32)) * inv;
    oy = (oy + __shfl_xor(oy, 32)) * inv;

    if (lane < 32) {
        ushort2 o;
        o.x = f2bf(ox);
        o.y = f2bf(oy);
        *(ushort2*)(ao + (size_t)e * 64 + l32 * 2) = o;
    }
}

// ---------------------------------------------------------------------------
// Wo GEMM via MFMA + fused residual: out = ef_in + attn(bf16) @ Wo.
// One wave per 16 rows x 64 cols. ef_in may alias out (same-thread rmw).
// ---------------------------------------------------------------------------
__global__ __launch_bounds__(256) void wo_mfma(
    const float* __restrict__ ef_in, const ushort* __restrict__ attn,
    const ushort* __restrict__ wofrag, float* __restrict__ efo)
{
    const int wave = threadIdx.x >> 6;
    const int lane = threadIdx.x & 63;
    const int r  = lane & 15;
    const int kg = lane >> 4;
    const int e0 = blockIdx.x * 64 + wave * 16;
    const int e  = e0 + r;
    const int ec = (e < NE) ? e : NE - 1;

    short8 afr[2];
    #pragma unroll
    for (int s = 0; s < 2; ++s)
        afr[s] = *(const short8*)(attn + (size_t)ec * 64 + s * 32 + kg * 8);

    const short8* wf = (const short8*)wofrag;
    f32x4 acc[4];
    #pragma unroll
    for (int t = 0; t < 4; ++t) acc[t] = (f32x4)(0.f);
    #pragma unroll
    for (int s = 0; s < 2; ++s) {
        #pragma unroll
        for (int t = 0; t < 4; ++t) {
            short8 b = wf[(size_t)(s * 4 + t) * 64 + lane];
            acc[t] = __builtin_amdgcn_mfma_f32_16x16x32_bf16(afr[s], b, acc[t], 0, 0, 0);
        }
    }

    const int orow = e0 + kg * 4;
    #pragma unroll
    for (int t = 0; t < 4; ++t) {
        const int c = t * 16 + r;
        #pragma unroll
        for (int j = 0; j < 4; ++j) {
            int row = orow + j;
            if (row < NE) {
                size_t off = (size_t)row * 64 + c;
                efo[off] = acc[t][j] + ef_in[off];
            }
        }
    }
}

// ---------------------------------------------------------------------------
extern "C" void kernel_launch(void* const* d_in, const int* in_sizes, int n_in,
                              void* d_out, int out_size, void* d_ws, size_t ws_size,
                              hipStream_t stream)
{
    const float* nodef   = (const float*)d_in[0];
    const float* ef      = (const float*)d_in[1];
    const int*   eidx    = (const int*)d_in[2];   // [2,E]
    const int*   adj_src = (const int*)d_in[4];
    const float* l1Wq = (const float*)d_in[6];
    const float* l1Wk = (const float*)d_in[7];
    const float* l1Wv = (const float*)d_in[8];
    const float* l1Wo = (const float*)d_in[9];
    const float* l2Wq = (const float*)d_in[10];
    const float* l2Wk = (const float*)d_in[11];
    const float* l2Wv = (const float*)d_in[12];
    const float* l2Wo = (const float*)d_in[13];

    ushort* q  = (ushort*)d_ws;                  // [E,64] bf16
    ushort* k  = q  + (size_t)NE * 64;
    ushort* v  = k  + (size_t)NE * 64;
    ushort* ao = v  + (size_t)NE * 64;           // attn out, bf16
    ushort* wf1 = ao + (size_t)NE * 64;          // 36864 each
    ushort* wf2 = wf1 + 36864;
    ushort* wo1 = wf2 + 36864;                   // 4096 each
    ushort* wo2 = wo1 + 4096;
    float* out = (float*)d_out;

    dim3 blk(256);
    const int gq = (NE + 127) / 128;  // 782  (128 rows / block, 4 waves x 32)
    const int ga = (NE + 3) / 4;      // 25000
    const int gw = (NE + 63) / 64;    // 1563

    // pack weights (bf16, fragment-ordered)
    prep_qkv_w<<<18, blk, 0, stream>>>(l1Wq, l1Wk, l1Wv, wf1);
    prep_qkv_w<<<18, blk, 0, stream>>>(l2Wq, l2Wk, l2Wv, wf2);
    prep_wo_w<<<2, blk, 0, stream>>>(l1Wo, wo1);
    prep_wo_w<<<2, blk, 0, stream>>>(l2Wo, wo2);

    // ---- layer 1 ----
    qkv_mfma<<<gq, blk, 0, stream>>>(ef, nodef, eidx, wf1, q, k, v);
    attn_kernel<<<ga, blk, 0, stream>>>(q, k, v, adj_src, ao);
    wo_mfma<<<gw, blk, 0, stream>>>(ef, ao, wo1, out);
    // ---- layer 2 ----
    qkv_mfma<<<gq, blk, 0, stream>>>(out, nodef, eidx, wf2, q, k, v);
    attn_kernel<<<ga, blk, 0, stream>>>(q, k, v, adj_src, ao);
    wo_mfma<<<gw, blk, 0, stream>>>(out, ao, wo2, out);
}

// Round 4
// 155.600 us; speedup vs baseline: 2.5079x; 1.0925x over previous
//
#include <hip/hip_runtime.h>

#define NE 100000   // edges
#define NN 50000    // nodes

typedef short short8 __attribute__((ext_vector_type(8)));
typedef float f32x4 __attribute__((ext_vector_type(4)));
typedef unsigned short ushort;
typedef unsigned int uint;

// fp32 -> bf16 bits, round-to-nearest-even
__device__ inline ushort f2bf(float f) {
    unsigned int u = __float_as_uint(f);
    u += 0x7FFFu + ((u >> 16) & 1u);
    return (ushort)(u >> 16);
}
__device__ inline float bf2f(ushort u) {
    return __uint_as_float((unsigned int)u << 16);
}

__device__ inline short8 pack_bf8(float4 a, float4 b) {
    short8 r;
    r[0] = (short)f2bf(a.x); r[1] = (short)f2bf(a.y);
    r[2] = (short)f2bf(a.z); r[3] = (short)f2bf(a.w);
    r[4] = (short)f2bf(b.x); r[5] = (short)f2bf(b.y);
    r[6] = (short)f2bf(b.z); r[7] = (short)f2bf(b.w);
    return r;
}

// ---------------------------------------------------------------------------
// Prep: pack W = [Wq|Wk|Wv] (each [192,64] fp32) into bf16 B-fragment order:
// wf[((s*12 + t)*64 + lane)*8 + j] = W[k = 32s + (lane>>4)*8 + j][n = 16t + (lane&15)]
// Byte layout: fragment f at bytes [f*1024, f*1024+1024), lane-major 16 B each.
// ---------------------------------------------------------------------------
__global__ __launch_bounds__(256) void prep_qkv_w(
    const float* __restrict__ Wq, const float* __restrict__ Wk,
    const float* __restrict__ Wv, ushort* __restrict__ wf)
{
    int idx = blockIdx.x * 256 + threadIdx.x;
    if (idx >= 6 * 12 * 64) return;
    int lane = idx & 63;
    int st = idx >> 6;
    int s = st / 12, t = st % 12;
    int n = t * 16 + (lane & 15);
    int kb = s * 32 + (lane >> 4) * 8;
    const float* w = (n < 64) ? Wq : (n < 128) ? Wk : Wv;
    int nn = n & 63;
    #pragma unroll
    for (int j = 0; j < 8; ++j)
        wf[(size_t)idx * 8 + j] = f2bf(w[(size_t)(kb + j) * 64 + nn]);
}

// Same packing for Wo [64,64]: 2 ksteps x 4 ntiles x 64 lanes = 512 slots.
__global__ __launch_bounds__(256) void prep_wo_w(
    const float* __restrict__ Wo, ushort* __restrict__ wf)
{
    int idx = blockIdx.x * 256 + threadIdx.x;
    if (idx >= 2 * 4 * 64) return;
    int lane = idx & 63;
    int st = idx >> 6;
    int s = st / 4, t = st % 4;
    int n = t * 16 + (lane & 15);
    int kb = s * 32 + (lane >> 4) * 8;
    #pragma unroll
    for (int j = 0; j < 8; ++j)
        wf[(size_t)idx * 8 + j] = f2bf(Wo[(size_t)(kb + j) * 64 + n]);
}

// ---------------------------------------------------------------------------
// QKV GEMM via MFMA. One wave per 32 edge-rows (two 16-row A tiles), all 192
// output cols. W fragments staged once per block into LDS (72 KB) via
// global_load_lds; K-loop reads B via conflict-free ds_read_b128.
// ---------------------------------------------------------------------------
__global__ __launch_bounds__(256, 2) void qkv_mfma(
    const float* __restrict__ ef, const float* __restrict__ nodef,
    const int* __restrict__ eidx, const ushort* __restrict__ wfrag,
    ushort* __restrict__ qo, ushort* __restrict__ ko, ushort* __restrict__ vo)
{
    __shared__ __align__(1024) ushort lds_w[36864];   // 72 fragments x 1 KB

    const int wave = threadIdx.x >> 6;
    const int lane = threadIdx.x & 63;

    // ---- stage W->LDS: wave w stages fragments [w*18, (w+1)*18) ----
    {
        const char* g = (const char*)wfrag + (size_t)lane * 16;
        char*       l = (char*)lds_w;
        #pragma unroll
        for (int i = 0; i < 18; ++i) {
            const int frag = wave * 18 + i;
            __builtin_amdgcn_global_load_lds(
                (const __attribute__((address_space(1))) uint*)(g + (size_t)frag * 1024),
                (__attribute__((address_space(3))) uint*)(l + (size_t)frag * 1024),
                16, 0, 0);
        }
    }

    const int r  = lane & 15;
    const int kg = lane >> 4;
    const int e0 = blockIdx.x * 128 + wave * 32;
    const int eA = e0 + r;
    const int eB = e0 + 16 + r;
    const int eAc = (eA < NE) ? eA : NE - 1;
    const int eBc = (eB < NE) ? eB : NE - 1;

    const float* pA[3] = { ef    + (size_t)eAc * 64,
                           nodef + (size_t)eidx[eAc] * 64,
                           nodef + (size_t)eidx[NE + eAc] * 64 };
    const float* pB[3] = { ef    + (size_t)eBc * 64,
                           nodef + (size_t)eidx[eBc] * 64,
                           nodef + (size_t)eidx[NE + eBc] * 64 };

    // preload ALL A fragments (6 k-steps x 2 tiles) before the barrier
    short8 a0[6], a1[6];
    #pragma unroll
    for (int s = 0; s < 6; ++s) {
        const float* ba = pA[s >> 1] + (s & 1) * 32 + kg * 8;
        const float* bb = pB[s >> 1] + (s & 1) * 32 + kg * 8;
        a0[s] = pack_bf8(*(const float4*)ba, *(const float4*)(ba + 4));
        a1[s] = pack_bf8(*(const float4*)bb, *(const float4*)(bb + 4));
    }

    f32x4 acc0[12], acc1[12];
    #pragma unroll
    for (int t = 0; t < 12; ++t) { acc0[t] = (f32x4)(0.f); acc1[t] = (f32x4)(0.f); }

    __syncthreads();   // drains global_load_lds queue, LDS now valid

    const char* lbase = (const char*)lds_w + lane * 16;
    #pragma unroll
    for (int s = 0; s < 6; ++s) {
        short8 b[12];
        #pragma unroll
        for (int t = 0; t < 12; ++t)
            b[t] = *(const short8*)(lbase + (size_t)(s * 12 + t) * 1024);
        #pragma unroll
        for (int t = 0; t < 12; ++t) {
            acc0[t] = __builtin_amdgcn_mfma_f32_16x16x32_bf16(a0[s], b[t], acc0[t], 0, 0, 0);
            acc1[t] = __builtin_amdgcn_mfma_f32_16x16x32_bf16(a1[s], b[t], acc1[t], 0, 0, 0);
        }
    }

    // D layout: col = lane&15 (=r), row = kg*4 + j
    const int orow0 = e0 + kg * 4;
    const int orow1 = e0 + 16 + kg * 4;
    #pragma unroll
    for (int t = 0; t < 12; ++t) {
        const int c = t * 16 + r;
        ushort* dst = (c < 64) ? (qo + c) : (c < 128) ? (ko + (c - 64)) : (vo + (c - 128));
        #pragma unroll
        for (int j = 0; j < 4; ++j) {
            int row0 = orow0 + j;
            int row1 = orow1 + j;
            if (row0 < NE) dst[(size_t)row0 * 64] = f2bf(acc0[t][j]);
            if (row1 < NE) dst[(size_t)row1 * 64] = f2bf(acc1[t][j]);
        }
    }
}

// ---------------------------------------------------------------------------
// Attention: one wave per dst edge (neighbors at adj slots e*8..e*8+7).
// lane = half*32 + h*8 + dd: dim-pair (2dd,2dd+1) of head h, neighbor parity
// `half`. All bf16 in/out, fp32 math.
// ---------------------------------------------------------------------------
__global__ __launch_bounds__(256) void attn_kernel(
    const ushort* __restrict__ q, const ushort* __restrict__ kbuf,
    const ushort* __restrict__ vbuf, const int* __restrict__ adj_src,
    ushort* __restrict__ ao)
{
    const int wid  = (blockIdx.x * 256 + threadIdx.x) >> 6;
    const int lane = threadIdx.x & 63;
    if (wid >= NE) return;
    const int e    = wid;
    const int half = lane >> 5;
    const int l32  = lane & 31;

    ushort2 qu = *(const ushort2*)(q + (size_t)e * 64 + l32 * 2);
    const float q0 = bf2f(qu.x), q1 = bf2f(qu.y);

    int nbr[4];
    float s[4];
    #pragma unroll
    for (int t = 0; t < 4; ++t) {
        nbr[t] = adj_src[e * 8 + 2 * t + half];
        ushort2 ku = *(const ushort2*)(kbuf + (size_t)nbr[t] * 64 + l32 * 2);
        float p = q0 * bf2f(ku.x) + q1 * bf2f(ku.y);
        p += __shfl_xor(p, 1);
        p += __shfl_xor(p, 2);
        p += __shfl_xor(p, 4);           // sum over the 8 lanes of this head
        s[t] = p * 0.25f;                // 1/sqrt(16)
    }

    float m = fmaxf(fmaxf(s[0], s[1]), fmaxf(s[2], s[3]));
    m = fmaxf(m, __shfl_xor(m, 32));     // combine neighbor parities
    float w[4], den = 0.f;
    #pragma unroll
    for (int t = 0; t < 4; ++t) { w[t] = __expf(s[t] - m); den += w[t]; }
    den += __shfl_xor(den, 32);
    const float inv = 1.f / den;

    float ox = 0.f, oy = 0.f;
    #pragma unroll
    for (int t = 0; t < 4; ++t) {
        ushort2 vu = *(const ushort2*)(vbuf + (size_t)nbr[t] * 64 + l32 * 2);
        ox = fmaf(w[t], bf2f(vu.x), ox);
        oy = fmaf(w[t], bf2f(vu.y), oy);
    }
    ox = (ox + __shfl_xor(ox, 32)) * inv;
    oy = (oy + __shfl_xor(oy, 32)) * inv;

    if (lane < 32) {
        ushort2 o;
        o.x = f2bf(ox);
        o.y = f2bf(oy);
        *(ushort2*)(ao + (size_t)e * 64 + l32 * 2) = o;
    }
}

// ---------------------------------------------------------------------------
// Wo GEMM via MFMA + fused residual: out = ef_in + attn(bf16) @ Wo.
// One wave per 16 rows x 64 cols. B-buffer is 8 KB -> L1-resident, no LDS.
// ---------------------------------------------------------------------------
__global__ __launch_bounds__(256) void wo_mfma(
    const float* __restrict__ ef_in, const ushort* __restrict__ attn,
    const ushort* __restrict__ wofrag, float* __restrict__ efo)
{
    const int wave = threadIdx.x >> 6;
    const int lane = threadIdx.x & 63;
    const int r  = lane & 15;
    const int kg = lane >> 4;
    const int e0 = blockIdx.x * 64 + wave * 16;
    const int e  = e0 + r;
    const int ec = (e < NE) ? e : NE - 1;

    short8 afr[2];
    #pragma unroll
    for (int s = 0; s < 2; ++s)
        afr[s] = *(const short8*)(attn + (size_t)ec * 64 + s * 32 + kg * 8);

    const short8* wf = (const short8*)wofrag;
    f32x4 acc[4];
    #pragma unroll
    for (int t = 0; t < 4; ++t) acc[t] = (f32x4)(0.f);
    #pragma unroll
    for (int s = 0; s < 2; ++s) {
        #pragma unroll
        for (int t = 0; t < 4; ++t) {
            short8 b = wf[(size_t)(s * 4 + t) * 64 + lane];
            acc[t] = __builtin_amdgcn_mfma_f32_16x16x32_bf16(afr[s], b, acc[t], 0, 0, 0);
        }
    }

    const int orow = e0 + kg * 4;
    #pragma unroll
    for (int t = 0; t < 4; ++t) {
        const int c = t * 16 + r;
        #pragma unroll
        for (int j = 0; j < 4; ++j) {
            int row = orow + j;
            if (row < NE) {
                size_t off = (size_t)row * 64 + c;
                efo[off] = acc[t][j] + ef_in[off];
            }
        }
    }
}

// ---------------------------------------------------------------------------
extern "C" void kernel_launch(void* const* d_in, const int* in_sizes, int n_in,
                              void* d_out, int out_size, void* d_ws, size_t ws_size,
                              hipStream_t stream)
{
    const float* nodef   = (const float*)d_in[0];
    const float* ef      = (const float*)d_in[1];
    const int*   eidx    = (const int*)d_in[2];   // [2,E]
    const int*   adj_src = (const int*)d_in[4];
    const float* l1Wq = (const float*)d_in[6];
    const float* l1Wk = (const float*)d_in[7];
    const float* l1Wv = (const float*)d_in[8];
    const float* l1Wo = (const float*)d_in[9];
    const float* l2Wq = (const float*)d_in[10];
    const float* l2Wk = (const float*)d_in[11];
    const float* l2Wv = (const float*)d_in[12];
    const float* l2Wo = (const float*)d_in[13];

    ushort* q  = (ushort*)d_ws;                  // [E,64] bf16
    ushort* k  = q  + (size_t)NE * 64;
    ushort* v  = k  + (size_t)NE * 64;
    ushort* ao = v  + (size_t)NE * 64;           // attn out, bf16
    ushort* wf1 = ao + (size_t)NE * 64;          // 36864 ushorts each
    ushort* wf2 = wf1 + 36864;
    ushort* wo1 = wf2 + 36864;                   // 4096 each
    ushort* wo2 = wo1 + 4096;
    float* out = (float*)d_out;

    dim3 blk(256);
    const int gq = (NE + 127) / 128;  // 782
    const int ga = (NE + 3) / 4;      // 25000
    const int gw = (NE + 63) / 64;    // 1563

    // pack weights (bf16, fragment-ordered)
    prep_qkv_w<<<18, blk, 0, stream>>>(l1Wq, l1Wk, l1Wv, wf1);
    prep_qkv_w<<<18, blk, 0, stream>>>(l2Wq, l2Wk, l2Wv, wf2);
    prep_wo_w<<<2, blk, 0, stream>>>(l1Wo, wo1);
    prep_wo_w<<<2, blk, 0, stream>>>(l2Wo, wo2);

    // ---- layer 1 ----
    qkv_mfma<<<gq, blk, 0, stream>>>(ef, nodef, eidx, wf1, q, k, v);
    attn_kernel<<<ga, blk, 0, stream>>>(q, k, v, adj_src, ao);
    wo_mfma<<<gw, blk, 0, stream>>>(ef, ao, wo1, out);
    // ---- layer 2 ----
    qkv_mfma<<<gq, blk, 0, stream>>>(out, nodef, eidx, wf2, q, k, v);
    attn_kernel<<<ga, blk, 0, stream>>>(q, k, v, adj_src, ao);
    wo_mfma<<<gw, blk, 0, stream>>>(out, ao, wo2, out);
}

// Round 5
// 148.640 us; speedup vs baseline: 2.6254x; 1.0468x over previous
//
#include <hip/hip_runtime.h>

#define NE 100000   // edges
#define NN 50000    // nodes

typedef short short8 __attribute__((ext_vector_type(8)));
typedef float f32x4 __attribute__((ext_vector_type(4)));
typedef unsigned short ushort;
typedef unsigned int uint;

// fp32 -> bf16 bits, round-to-nearest-even
__device__ inline ushort f2bf(float f) {
    unsigned int u = __float_as_uint(f);
    u += 0x7FFFu + ((u >> 16) & 1u);
    return (ushort)(u >> 16);
}
__device__ inline float bf2f(ushort u) {
    return __uint_as_float((unsigned int)u << 16);
}

__device__ inline short8 pack_bf8(float4 a, float4 b) {
    short8 r;
    r[0] = (short)f2bf(a.x); r[1] = (short)f2bf(a.y);
    r[2] = (short)f2bf(a.z); r[3] = (short)f2bf(a.w);
    r[4] = (short)f2bf(b.x); r[5] = (short)f2bf(b.y);
    r[6] = (short)f2bf(b.z); r[7] = (short)f2bf(b.w);
    return r;
}

// ---------------------------------------------------------------------------
// Prep: pack W = [Wq|Wk|Wv] (each [192,64] fp32) into bf16 B-fragment order:
// wf[((s*12 + t)*64 + lane)*8 + j] = W[k = 32s + (lane>>4)*8 + j][n = 16t + (lane&15)]
// ---------------------------------------------------------------------------
__global__ __launch_bounds__(256) void prep_qkv_w(
    const float* __restrict__ Wq, const float* __restrict__ Wk,
    const float* __restrict__ Wv, ushort* __restrict__ wf)
{
    int idx = blockIdx.x * 256 + threadIdx.x;
    if (idx >= 6 * 12 * 64) return;
    int lane = idx & 63;
    int st = idx >> 6;
    int s = st / 12, t = st % 12;
    int n = t * 16 + (lane & 15);
    int kb = s * 32 + (lane >> 4) * 8;
    const float* w = (n < 64) ? Wq : (n < 128) ? Wk : Wv;
    int nn = n & 63;
    #pragma unroll
    for (int j = 0; j < 8; ++j)
        wf[(size_t)idx * 8 + j] = f2bf(w[(size_t)(kb + j) * 64 + nn]);
}

// Same packing for Wo [64,64]: 2 ksteps x 4 ntiles x 64 lanes = 512 slots.
__global__ __launch_bounds__(256) void prep_wo_w(
    const float* __restrict__ Wo, ushort* __restrict__ wf)
{
    int idx = blockIdx.x * 256 + threadIdx.x;
    if (idx >= 2 * 4 * 64) return;
    int lane = idx & 63;
    int st = idx >> 6;
    int s = st / 4, t = st % 4;
    int n = t * 16 + (lane & 15);
    int kb = s * 32 + (lane >> 4) * 8;
    #pragma unroll
    for (int j = 0; j < 8; ++j)
        wf[(size_t)idx * 8 + j] = f2bf(Wo[(size_t)(kb + j) * 64 + n]);
}

// ---------------------------------------------------------------------------
// QKV GEMM via MFMA, occupancy-first structure.
// Block = 256 threads / 4 waves, 64 edge-rows. Wave w owns n-tiles 3w..3w+2
// (48 of the 192 output cols) with its 18 B-fragments held in VGPRs.
// A-rows gathered+bf16-converted cooperatively into LDS (24.75 KB, padded
// regions -> conflict-free ds_write AND ds_read).
// ---------------------------------------------------------------------------
__global__ __launch_bounds__(256, 3) void qkv_mfma(
    const float* __restrict__ ef, const float* __restrict__ nodef,
    const int* __restrict__ eidx, const ushort* __restrict__ wfrag,
    ushort* __restrict__ qo, ushort* __restrict__ ko, ushort* __restrict__ vo)
{
    // 24 regions (4 tiles x 3 sources x 2 halves) of 1056 B (1024 + 32 pad)
    __shared__ __align__(16) char lds_a[24 * 1056];

    const int tid = threadIdx.x;
    const int l   = tid & 63;     // lane
    const int w   = tid >> 6;     // wave id = A-tile it stages = n-group it computes

    // ---- B fragments into VGPRs: wave w -> n-tiles {3w,3w+1,3w+2}, 6 ksteps
    short8 Bf[6][3];
    #pragma unroll
    for (int s = 0; s < 6; ++s)
        #pragma unroll
        for (int n = 0; n < 3; ++n)
            Bf[s][n] = *(const short8*)((const char*)wfrag +
                        (size_t)((s * 12 + 3 * w + n) * 64 + l) * 16);

    // ---- stage A: thread = (row r64 = tid>>2, k-part p = tid&3) ----
    {
        const int r64 = tid >> 2;
        const int p   = tid & 3;
        const int row = blockIdx.x * 64 + r64;
        const int rc  = (row < NE) ? row : NE - 1;
        const float* srcs[3] = { ef    + (size_t)rc * 64,
                                 nodef + (size_t)eidx[rc] * 64,
                                 nodef + (size_t)eidx[NE + rc] * 64 };
        #pragma unroll
        for (int c = 0; c < 3; ++c) {
            const float* sp = srcs[c] + p * 16;
            float4 f0 = *(const float4*)(sp + 0);
            float4 f1 = *(const float4*)(sp + 4);
            float4 f2 = *(const float4*)(sp + 8);
            float4 f3 = *(const float4*)(sp + 12);
            short8 lo = pack_bf8(f0, f1);
            short8 hi = pack_bf8(f2, f3);
            const int regbase = (w * 3 + c) * 2;   // tile = w (rows 16w..16w+15)
            *(short8*)(lds_a + (size_t)(regbase + 0) * 1056 + l * 16) = lo;
            *(short8*)(lds_a + (size_t)(regbase + 1) * 1056 + l * 16) = hi;
        }
    }

    f32x4 acc[4][3];
    #pragma unroll
    for (int T = 0; T < 4; ++T)
        #pragma unroll
        for (int n = 0; n < 3; ++n) acc[T][n] = (f32x4)(0.f);

    __syncthreads();

    // ---- compute: frag(T,s) at region (T*3+(s>>1))*2+(kg&1),
    //      slot r*4 + (s&1)*2 + (kg>>1)  (== writer's linear slot) ----
    const int r  = l & 15;
    const int kg = l >> 4;
    #pragma unroll
    for (int s = 0; s < 6; ++s) {
        short8 Af[4];
        #pragma unroll
        for (int T = 0; T < 4; ++T) {
            const int region = (T * 3 + (s >> 1)) * 2 + (kg & 1);
            const int slot   = r * 4 + (s & 1) * 2 + (kg >> 1);
            Af[T] = *(const short8*)(lds_a + (size_t)region * 1056 + slot * 16);
        }
        #pragma unroll
        for (int T = 0; T < 4; ++T)
            #pragma unroll
            for (int n = 0; n < 3; ++n)
                acc[T][n] = __builtin_amdgcn_mfma_f32_16x16x32_bf16(
                                Af[T], Bf[s][n], acc[T][n], 0, 0, 0);
    }

    // ---- store: D(m,n): edge-row = 16T + kg*4 + jj, col = (3w+n)*16 + r ----
    const int e0 = blockIdx.x * 64;
    #pragma unroll
    for (int T = 0; T < 4; ++T) {
        #pragma unroll
        for (int n = 0; n < 3; ++n) {
            const int c = (3 * w + n) * 16 + r;
            ushort* dst = (c < 64) ? (qo + c) : (c < 128) ? (ko + (c - 64))
                                              : (vo + (c - 128));
            #pragma unroll
            for (int jj = 0; jj < 4; ++jj) {
                const int row = e0 + T * 16 + kg * 4 + jj;
                if (row < NE) dst[(size_t)row * 64] = f2bf(acc[T][n][jj]);
            }
        }
    }
}

// ---------------------------------------------------------------------------
// Attention: one wave per dst edge (neighbors at adj slots e*8..e*8+7).
// lane = half*32 + h*8 + dd: dim-pair (2dd,2dd+1) of head h, neighbor parity
// `half`. All bf16 in/out, fp32 math.
// ---------------------------------------------------------------------------
__global__ __launch_bounds__(256) void attn_kernel(
    const ushort* __restrict__ q, const ushort* __restrict__ kbuf,
    const ushort* __restrict__ vbuf, const int* __restrict__ adj_src,
    ushort* __restrict__ ao)
{
    const int wid  = (blockIdx.x * 256 + threadIdx.x) >> 6;
    const int lane = threadIdx.x & 63;
    if (wid >= NE) return;
    const int e    = wid;
    const int half = lane >> 5;
    const int l32  = lane & 31;

    ushort2 qu = *(const ushort2*)(q + (size_t)e * 64 + l32 * 2);
    const float q0 = bf2f(qu.x), q1 = bf2f(qu.y);

    int nbr[4];
    float s[4];
    #pragma unroll
    for (int t = 0; t < 4; ++t) {
        nbr[t] = adj_src[e * 8 + 2 * t + half];
        ushort2 ku = *(const ushort2*)(kbuf + (size_t)nbr[t] * 64 + l32 * 2);
        float p = q0 * bf2f(ku.x) + q1 * bf2f(ku.y);
        p += __shfl_xor(p, 1);
        p += __shfl_xor(p, 2);
        p += __shfl_xor(p, 4);           // sum over the 8 lanes of this head
        s[t] = p * 0.25f;                // 1/sqrt(16)
    }

    float m = fmaxf(fmaxf(s[0], s[1]), fmaxf(s[2], s[3]));
    m = fmaxf(m, __shfl_xor(m, 32));     // combine neighbor parities
    float w[4], den = 0.f;
    #pragma unroll
    for (int t = 0; t < 4; ++t) { w[t] = __expf(s[t] - m); den += w[t]; }
    den += __shfl_xor(den, 32);
    const float inv = 1.f / den;

    float ox = 0.f, oy = 0.f;
    #pragma unroll
    for (int t = 0; t < 4; ++t) {
        ushort2 vu = *(const ushort2*)(vbuf + (size_t)nbr[t] * 64 + l32 * 2);
        ox = fmaf(w[t], bf2f(vu.x), ox);
        oy = fmaf(w[t], bf2f(vu.y), oy);
    }
    ox = (ox + __shfl_xor(ox, 32)) * inv;
    oy = (oy + __shfl_xor(oy, 32)) * inv;

    if (lane < 32) {
        ushort2 o;
        o.x = f2bf(ox);
        o.y = f2bf(oy);
        *(ushort2*)(ao + (size_t)e * 64 + l32 * 2) = o;
    }
}

// ---------------------------------------------------------------------------
// Wo GEMM via MFMA + fused residual: out = ef_in + attn(bf16) @ Wo.
// One wave per 16 rows x 64 cols. B-buffer is 8 KB -> L1/L2-resident.
// ---------------------------------------------------------------------------
__global__ __launch_bounds__(256) void wo_mfma(
    const float* __restrict__ ef_in, const ushort* __restrict__ attn,
    const ushort* __restrict__ wofrag, float* __restrict__ efo)
{
    const int wave = threadIdx.x >> 6;
    const int lane = threadIdx.x & 63;
    const int r  = lane & 15;
    const int kg = lane >> 4;
    const int e0 = blockIdx.x * 64 + wave * 16;
    const int e  = e0 + r;
    const int ec = (e < NE) ? e : NE - 1;

    short8 afr[2];
    #pragma unroll
    for (int s = 0; s < 2; ++s)
        afr[s] = *(const short8*)(attn + (size_t)ec * 64 + s * 32 + kg * 8);

    const short8* wf = (const short8*)wofrag;
    f32x4 acc[4];
    #pragma unroll
    for (int t = 0; t < 4; ++t) acc[t] = (f32x4)(0.f);
    #pragma unroll
    for (int s = 0; s < 2; ++s) {
        #pragma unroll
        for (int t = 0; t < 4; ++t) {
            short8 b = wf[(size_t)(s * 4 + t) * 64 + lane];
            acc[t] = __builtin_amdgcn_mfma_f32_16x16x32_bf16(afr[s], b, acc[t], 0, 0, 0);
        }
    }

    const int orow = e0 + kg * 4;
    #pragma unroll
    for (int t = 0; t < 4; ++t) {
        const int c = t * 16 + r;
        #pragma unroll
        for (int j = 0; j < 4; ++j) {
            int row = orow + j;
            if (row < NE) {
                size_t off = (size_t)row * 64 + c;
                efo[off] = acc[t][j] + ef_in[off];
            }
        }
    }
}

// ---------------------------------------------------------------------------
extern "C" void kernel_launch(void* const* d_in, const int* in_sizes, int n_in,
                              void* d_out, int out_size, void* d_ws, size_t ws_size,
                              hipStream_t stream)
{
    const float* nodef   = (const float*)d_in[0];
    const float* ef      = (const float*)d_in[1];
    const int*   eidx    = (const int*)d_in[2];   // [2,E]
    const int*   adj_src = (const int*)d_in[4];
    const float* l1Wq = (const float*)d_in[6];
    const float* l1Wk = (const float*)d_in[7];
    const float* l1Wv = (const float*)d_in[8];
    const float* l1Wo = (const float*)d_in[9];
    const float* l2Wq = (const float*)d_in[10];
    const float* l2Wk = (const float*)d_in[11];
    const float* l2Wv = (const float*)d_in[12];
    const float* l2Wo = (const float*)d_in[13];

    ushort* q  = (ushort*)d_ws;                  // [E,64] bf16
    ushort* k  = q  + (size_t)NE * 64;
    ushort* v  = k  + (size_t)NE * 64;
    ushort* ao = v  + (size_t)NE * 64;           // attn out, bf16
    ushort* wf1 = ao + (size_t)NE * 64;          // 36864 ushorts each
    ushort* wf2 = wf1 + 36864;
    ushort* wo1 = wf2 + 36864;                   // 4096 each
    ushort* wo2 = wo1 + 4096;
    float* out = (float*)d_out;

    dim3 blk(256);
    const int gq = (NE + 63) / 64;    // 1563 (64 rows / block)
    const int ga = (NE + 3) / 4;      // 25000
    const int gw = (NE + 63) / 64;    // 1563

    // pack weights (bf16, fragment-ordered)
    prep_qkv_w<<<18, blk, 0, stream>>>(l1Wq, l1Wk, l1Wv, wf1);
    prep_qkv_w<<<18, blk, 0, stream>>>(l2Wq, l2Wk, l2Wv, wf2);
    prep_wo_w<<<2, blk, 0, stream>>>(l1Wo, wo1);
    prep_wo_w<<<2, blk, 0, stream>>>(l2Wo, wo2);

    // ---- layer 1 ----
    qkv_mfma<<<gq, blk, 0, stream>>>(ef, nodef, eidx, wf1, q, k, v);
    attn_kernel<<<ga, blk, 0, stream>>>(q, k, v, adj_src, ao);
    wo_mfma<<<gw, blk, 0, stream>>>(ef, ao, wo1, out);
    // ---- layer 2 ----
    qkv_mfma<<<gq, blk, 0, stream>>>(out, nodef, eidx, wf2, q, k, v);
    attn_kernel<<<ga, blk, 0, stream>>>(q, k, v, adj_src, ao);
    wo_mfma<<<gw, blk, 0, stream>>>(out, ao, wo2, out);
}

// Round 6
// 142.284 us; speedup vs baseline: 2.7426x; 1.0447x over previous
//
#include <hip/hip_runtime.h>

#define NE 100000   // edges
#define NN 50000    // nodes

typedef short short8 __attribute__((ext_vector_type(8)));
typedef float f32x4 __attribute__((ext_vector_type(4)));
typedef unsigned short ushort;
typedef unsigned int uint;

// fp32 -> bf16 bits, round-to-nearest-even
__device__ inline ushort f2bf(float f) {
    unsigned int u = __float_as_uint(f);
    u += 0x7FFFu + ((u >> 16) & 1u);
    return (ushort)(u >> 16);
}
__device__ inline float bf2f(ushort u) {
    return __uint_as_float((unsigned int)u << 16);
}

__device__ inline short8 pack_bf8(float4 a, float4 b) {
    short8 r;
    r[0] = (short)f2bf(a.x); r[1] = (short)f2bf(a.y);
    r[2] = (short)f2bf(a.z); r[3] = (short)f2bf(a.w);
    r[4] = (short)f2bf(b.x); r[5] = (short)f2bf(b.y);
    r[6] = (short)f2bf(b.z); r[7] = (short)f2bf(b.w);
    return r;
}

// ---------------------------------------------------------------------------
// Prep (single launch): pack both layers' QKV + Wo weights into bf16
// B-fragment order.
// qkv: wf[((s*12 + t)*64 + lane)*8 + j] = W[k=32s+(lane>>4)*8+j][n=16t+(lane&15)]
// wo : same with 4 n-tiles, 2 ksteps.
// ---------------------------------------------------------------------------
__device__ inline void pack_qkv_slot(int slot, const float* Wq, const float* Wk,
                                     const float* Wv, ushort* wf)
{
    int lane = slot & 63;
    int st = slot >> 6;
    int s = st / 12, t = st % 12;
    int n = t * 16 + (lane & 15);
    int kb = s * 32 + (lane >> 4) * 8;
    const float* w = (n < 64) ? Wq : (n < 128) ? Wk : Wv;
    int nn = n & 63;
    #pragma unroll
    for (int j = 0; j < 8; ++j)
        wf[(size_t)slot * 8 + j] = f2bf(w[(size_t)(kb + j) * 64 + nn]);
}

__device__ inline void pack_wo_slot(int slot, const float* Wo, ushort* wf)
{
    int lane = slot & 63;
    int st = slot >> 6;
    int s = st / 4, t = st % 4;
    int n = t * 16 + (lane & 15);
    int kb = s * 32 + (lane >> 4) * 8;
    #pragma unroll
    for (int j = 0; j < 8; ++j)
        wf[(size_t)slot * 8 + j] = f2bf(Wo[(size_t)(kb + j) * 64 + n]);
}

__global__ __launch_bounds__(256) void prep_all(
    const float* __restrict__ l1Wq, const float* __restrict__ l1Wk,
    const float* __restrict__ l1Wv, const float* __restrict__ l1Wo,
    const float* __restrict__ l2Wq, const float* __restrict__ l2Wk,
    const float* __restrict__ l2Wv, const float* __restrict__ l2Wo,
    ushort* __restrict__ wf1, ushort* __restrict__ wf2,
    ushort* __restrict__ wo1, ushort* __restrict__ wo2)
{
    int idx = blockIdx.x * 256 + threadIdx.x;
    if (idx < 4608)            pack_qkv_slot(idx,         l1Wq, l1Wk, l1Wv, wf1);
    else if (idx < 9216)       pack_qkv_slot(idx - 4608,  l2Wq, l2Wk, l2Wv, wf2);
    else if (idx < 9728)       pack_wo_slot (idx - 9216,  l1Wo, wo1);
    else if (idx < 10240)      pack_wo_slot (idx - 9728,  l2Wo, wo2);
}

// ---------------------------------------------------------------------------
// QKV GEMM via MFMA. Block = 256 threads / 4 waves, 32 edge-rows.
// Wave w owns n-tiles {3w,3w+1,3w+2} with its 18 B-fragments in VGPRs
// (acc 24 + Bf 72 + Af 8 ~= 150 VGPR -> fits the ,3 cap of 168).
// A staged as padded [32][200] bf16 LDS tile (12.5 KB, <=2-way banked).
// ---------------------------------------------------------------------------
__global__ __launch_bounds__(256, 3) void qkv_mfma(
    const float* __restrict__ ef, const float* __restrict__ nodef,
    const int* __restrict__ eidx, const ushort* __restrict__ wfrag,
    ushort* __restrict__ qo, ushort* __restrict__ ko, ushort* __restrict__ vo)
{
    __shared__ __align__(16) ushort lds_a[32 * 200];   // row stride 200 (=400 B)

    const int tid = threadIdx.x;
    const int l   = tid & 63;
    const int w   = tid >> 6;

    // ---- B fragments -> VGPRs: wave w = n-tiles {3w..3w+2}, 6 ksteps ----
    short8 Bf[6][3];
    #pragma unroll
    for (int s = 0; s < 6; ++s)
        #pragma unroll
        for (int n = 0; n < 3; ++n)
            Bf[s][n] = *(const short8*)((const char*)wfrag +
                        (size_t)((s * 12 + 3 * w + n) * 64 + l) * 16);

    // ---- stage A: thread = (row r = tid>>3, part p = tid&7) ----
    {
        const int r   = tid >> 3;
        const int p   = tid & 7;
        const int row = blockIdx.x * 32 + r;
        const int rc  = (row < NE) ? row : NE - 1;
        const float* srcs[3] = { ef    + (size_t)rc * 64,
                                 nodef + (size_t)eidx[rc] * 64,
                                 nodef + (size_t)eidx[NE + rc] * 64 };
        #pragma unroll
        for (int c = 0; c < 3; ++c) {
            const float* sp = srcs[c] + p * 8;
            float4 f0 = *(const float4*)(sp + 0);
            float4 f1 = *(const float4*)(sp + 4);
            *(short8*)(lds_a + r * 200 + c * 64 + p * 8) = pack_bf8(f0, f1);
        }
    }

    f32x4 acc[2][3];
    #pragma unroll
    for (int T = 0; T < 2; ++T)
        #pragma unroll
        for (int n = 0; n < 3; ++n) acc[T][n] = (f32x4)(0.f);

    __syncthreads();

    const int rr = l & 15;
    const int kg = l >> 4;
    #pragma unroll
    for (int s = 0; s < 6; ++s) {
        short8 Af[2];
        #pragma unroll
        for (int T = 0; T < 2; ++T)
            Af[T] = *(const short8*)(lds_a + (T * 16 + rr) * 200 + s * 32 + kg * 8);
        #pragma unroll
        for (int T = 0; T < 2; ++T)
            #pragma unroll
            for (int n = 0; n < 3; ++n)
                acc[T][n] = __builtin_amdgcn_mfma_f32_16x16x32_bf16(
                                Af[T], Bf[s][n], acc[T][n], 0, 0, 0);
    }

    // ---- store: edge-row = e0 + 16T + kg*4 + jj, col = (3w+n)*16 + rr ----
    const int e0 = blockIdx.x * 32;
    #pragma unroll
    for (int T = 0; T < 2; ++T) {
        #pragma unroll
        for (int n = 0; n < 3; ++n) {
            const int c = (3 * w + n) * 16 + rr;
            ushort* dst = (c < 64) ? (qo + c) : (c < 128) ? (ko + (c - 64))
                                              : (vo + (c - 128));
            #pragma unroll
            for (int jj = 0; jj < 4; ++jj) {
                const int row = e0 + T * 16 + kg * 4 + jj;
                if (row < NE) dst[(size_t)row * 64] = f2bf(acc[T][n][jj]);
            }
        }
    }
}

// ---------------------------------------------------------------------------
// Attention: one wave per dst edge (neighbors at adj slots e*8..e*8+7).
// lane = half*32 + h*8 + dd: dim-pair (2dd,2dd+1) of head h; half h owns
// neighbors {4*half..4*half+3} (order-invariant). bf16 in/out, fp32 math.
// ---------------------------------------------------------------------------
__global__ __launch_bounds__(256) void attn_kernel(
    const ushort* __restrict__ q, const ushort* __restrict__ kbuf,
    const ushort* __restrict__ vbuf, const int* __restrict__ adj_src,
    ushort* __restrict__ ao)
{
    const int wid  = (blockIdx.x * 256 + threadIdx.x) >> 6;
    const int lane = threadIdx.x & 63;
    if (wid >= NE) return;
    const int e    = wid;
    const int half = lane >> 5;
    const int l32  = lane & 31;

    // all 4 of this half's neighbor indices in ONE load
    const int4 nb = *(const int4*)(adj_src + e * 8 + half * 4);
    const int nbr[4] = { nb.x, nb.y, nb.z, nb.w };

    ushort2 qu = *(const ushort2*)(q + (size_t)e * 64 + l32 * 2);
    const float q0 = bf2f(qu.x), q1 = bf2f(qu.y);

    // issue K and V gathers up front; V latency hides under softmax
    ushort2 ku[4], vu[4];
    #pragma unroll
    for (int t = 0; t < 4; ++t) {
        ku[t] = *(const ushort2*)(kbuf + (size_t)nbr[t] * 64 + l32 * 2);
        vu[t] = *(const ushort2*)(vbuf + (size_t)nbr[t] * 64 + l32 * 2);
    }

    float s[4];
    #pragma unroll
    for (int t = 0; t < 4; ++t) {
        float p = q0 * bf2f(ku[t].x) + q1 * bf2f(ku[t].y);
        p += __shfl_xor(p, 1);
        p += __shfl_xor(p, 2);
        p += __shfl_xor(p, 4);           // sum over the 8 lanes of this head
        s[t] = p * 0.25f;                // 1/sqrt(16)
    }

    float m = fmaxf(fmaxf(s[0], s[1]), fmaxf(s[2], s[3]));
    m = fmaxf(m, __shfl_xor(m, 32));     // combine the two neighbor halves
    float wgt[4], den = 0.f;
    #pragma unroll
    for (int t = 0; t < 4; ++t) { wgt[t] = __expf(s[t] - m); den += wgt[t]; }
    den += __shfl_xor(den, 32);
    const float inv = 1.f / den;

    float ox = 0.f, oy = 0.f;
    #pragma unroll
    for (int t = 0; t < 4; ++t) {
        ox = fmaf(wgt[t], bf2f(vu[t].x), ox);
        oy = fmaf(wgt[t], bf2f(vu[t].y), oy);
    }
    ox = (ox + __shfl_xor(ox, 32)) * inv;
    oy = (oy + __shfl_xor(oy, 32)) * inv;

    if (lane < 32) {
        ushort2 o;
        o.x = f2bf(ox);
        o.y = f2bf(oy);
        *(ushort2*)(ao + (size_t)e * 64 + l32 * 2) = o;
    }
}

// ---------------------------------------------------------------------------
// Wo GEMM via MFMA + fused residual: out = ef_in + attn(bf16) @ Wo.
// One wave per 16 rows x 64 cols. B-buffer is 8 KB -> L1/L2-resident.
// ---------------------------------------------------------------------------
__global__ __launch_bounds__(256) void wo_mfma(
    const float* __restrict__ ef_in, const ushort* __restrict__ attn,
    const ushort* __restrict__ wofrag, float* __restrict__ efo)
{
    const int wave = threadIdx.x >> 6;
    const int lane = threadIdx.x & 63;
    const int r  = lane & 15;
    const int kg = lane >> 4;
    const int e0 = blockIdx.x * 64 + wave * 16;
    const int e  = e0 + r;
    const int ec = (e < NE) ? e : NE - 1;

    short8 afr[2];
    #pragma unroll
    for (int s = 0; s < 2; ++s)
        afr[s] = *(const short8*)(attn + (size_t)ec * 64 + s * 32 + kg * 8);

    const short8* wf = (const short8*)wofrag;
    f32x4 acc[4];
    #pragma unroll
    for (int t = 0; t < 4; ++t) acc[t] = (f32x4)(0.f);
    #pragma unroll
    for (int s = 0; s < 2; ++s) {
        #pragma unroll
        for (int t = 0; t < 4; ++t) {
            short8 b = wf[(size_t)(s * 4 + t) * 64 + lane];
            acc[t] = __builtin_amdgcn_mfma_f32_16x16x32_bf16(afr[s], b, acc[t], 0, 0, 0);
        }
    }

    const int orow = e0 + kg * 4;
    #pragma unroll
    for (int t = 0; t < 4; ++t) {
        const int c = t * 16 + r;
        #pragma unroll
        for (int j = 0; j < 4; ++j) {
            int row = orow + j;
            if (row < NE) {
                size_t off = (size_t)row * 64 + c;
                efo[off] = acc[t][j] + ef_in[off];
            }
        }
    }
}

// ---------------------------------------------------------------------------
extern "C" void kernel_launch(void* const* d_in, const int* in_sizes, int n_in,
                              void* d_out, int out_size, void* d_ws, size_t ws_size,
                              hipStream_t stream)
{
    const float* nodef   = (const float*)d_in[0];
    const float* ef      = (const float*)d_in[1];
    const int*   eidx    = (const int*)d_in[2];   // [2,E]
    const int*   adj_src = (const int*)d_in[4];
    const float* l1Wq = (const float*)d_in[6];
    const float* l1Wk = (const float*)d_in[7];
    const float* l1Wv = (const float*)d_in[8];
    const float* l1Wo = (const float*)d_in[9];
    const float* l2Wq = (const float*)d_in[10];
    const float* l2Wk = (const float*)d_in[11];
    const float* l2Wv = (const float*)d_in[12];
    const float* l2Wo = (const float*)d_in[13];

    ushort* q  = (ushort*)d_ws;                  // [E,64] bf16
    ushort* k  = q  + (size_t)NE * 64;
    ushort* v  = k  + (size_t)NE * 64;
    ushort* ao = v  + (size_t)NE * 64;           // attn out, bf16
    ushort* wf1 = ao + (size_t)NE * 64;          // 36864 ushorts each
    ushort* wf2 = wf1 + 36864;
    ushort* wo1 = wf2 + 36864;                   // 4096 each
    ushort* wo2 = wo1 + 4096;
    float* out = (float*)d_out;

    dim3 blk(256);
    const int gq = (NE + 31) / 32;    // 3125 (32 rows / block)
    const int ga = (NE + 3) / 4;      // 25000
    const int gw = (NE + 63) / 64;    // 1563

    // pack all weights in ONE dispatch (bf16, fragment-ordered)
    prep_all<<<40, blk, 0, stream>>>(l1Wq, l1Wk, l1Wv, l1Wo,
                                     l2Wq, l2Wk, l2Wv, l2Wo,
                                     wf1, wf2, wo1, wo2);

    // ---- layer 1 ----
    qkv_mfma<<<gq, blk, 0, stream>>>(ef, nodef, eidx, wf1, q, k, v);
    attn_kernel<<<ga, blk, 0, stream>>>(q, k, v, adj_src, ao);
    wo_mfma<<<gw, blk, 0, stream>>>(ef, ao, wo1, out);
    // ---- layer 2 ----
    qkv_mfma<<<gq, blk, 0, stream>>>(out, nodef, eidx, wf2, q, k, v);
    attn_kernel<<<ga, blk, 0, stream>>>(q, k, v, adj_src, ao);
    wo_mfma<<<gw, blk, 0, stream>>>(out, ao, wo2, out);
}